// Round 6
// baseline (262.169 us; speedup 1.0000x reference)
//
#include <hip/hip_runtime.h>
#include <cstdint>
#include <cstddef>

typedef __bf16 bf16;
typedef __bf16 bf16x8 __attribute__((ext_vector_type(8)));
typedef float f32x4 __attribute__((ext_vector_type(4)));

#define DEVI static __device__ __forceinline__

// pack two f32 -> two bf16 (RTNE) in one uint
DEVI unsigned int cvt_pk_bf16(float lo, float hi) {
  unsigned int bl = __float_as_uint(lo);
  bl += 0x7fffu + ((bl >> 16) & 1u);
  unsigned int bh = __float_as_uint(hi);
  bh += 0x7fffu + ((bh >> 16) & 1u);
  return (bl >> 16) | (bh & 0xffff0000u);
}
DEVI float bf_lo(unsigned int u) { return __uint_as_float(u << 16); }
DEVI float bf_hi(unsigned int u) { return __uint_as_float(u & 0xffff0000u); }

// ---------------------------------------------------------------------------
// QKV f32 -> bf16 planes (3 x 2048x1024). grid 3072 x 256, 8 elems/thread.
// ---------------------------------------------------------------------------
__global__ __launch_bounds__(256) void cvt_in_k(
    const float* __restrict__ Q, const float* __restrict__ K,
    const float* __restrict__ V, bf16* __restrict__ out)
{
  unsigned t = blockIdx.x * 256 + threadIdx.x;
  int plane = t >> 18;
  size_t off = (size_t)(t & 262143) * 8;
  const float* src = (plane == 0) ? Q : (plane == 1) ? K : V;
  float4 a = *(const float4*)(src + off);
  float4 b = *(const float4*)(src + off + 4);
  uint4 o;
  o.x = cvt_pk_bf16(a.x, a.y); o.y = cvt_pk_bf16(a.z, a.w);
  o.z = cvt_pk_bf16(b.x, b.y); o.w = cvt_pk_bf16(b.z, b.w);
  *(uint4*)(out + ((size_t)plane << 21) + off) = o;
}

// ---------------------------------------------------------------------------
// W transpose prepass: W (1024x1024 f32, [k][n]) -> Wt (bf16 [n][k]).
// ---------------------------------------------------------------------------
__global__ __launch_bounds__(256) void wtr_k(
    const float* __restrict__ Wq, const float* __restrict__ Wk,
    const float* __restrict__ Wv, const float* __restrict__ Wo,
    bf16* __restrict__ Wt)
{
  const int z = blockIdx.z;
  const float* W = (z == 0) ? Wq : (z == 1) ? Wk : (z == 2) ? Wv : Wo;
  bf16* out = Wt + ((size_t)z << 20);
  const int n0 = blockIdx.x * 64, k0 = blockIdx.y * 64;
  __shared__ bf16 Ts[64 * 72];
  const int tid = threadIdx.x;
  #pragma unroll
  for (int i = 0; i < 4; ++i) {
    int t = tid + i * 256;
    int kr = t >> 4, nc = t & 15;
    float4 v = *(const float4*)(W + (size_t)(k0 + kr) * 1024 + n0 + nc * 4);
    Ts[(nc * 4 + 0) * 72 + kr] = (bf16)v.x;
    Ts[(nc * 4 + 1) * 72 + kr] = (bf16)v.y;
    Ts[(nc * 4 + 2) * 72 + kr] = (bf16)v.z;
    Ts[(nc * 4 + 3) * 72 + kr] = (bf16)v.w;
  }
  __syncthreads();
  const int n = tid >> 2, kc = tid & 3;
  *(uint4*)(out + (size_t)(n0 + n) * 1024 + k0 + kc * 16) =
      *(const uint4*)(&Ts[n * 72 + kc * 16]);
  *(uint4*)(out + (size_t)(n0 + n) * 1024 + k0 + kc * 16 + 8) =
      *(const uint4*)(&Ts[n * 72 + kc * 16 + 8]);
}

// ---------------------------------------------------------------------------
// Fused projection GEMM, all-bf16 operands, register-prefetch pipeline.
// grid (16,32,3): z=0 Q->qh, z=1 K->kh, z=2 V->vT(B,H,HD,S).
// ---------------------------------------------------------------------------
__global__ __launch_bounds__(256) void proj_gemm_k(
    const bf16* __restrict__ Abf, const bf16* __restrict__ Wt,
    const float* __restrict__ bq, const float* __restrict__ bk,
    const float* __restrict__ bv, bf16* __restrict__ outbase)
{
  const int z = blockIdx.z;
  const bf16* A  = Abf + ((size_t)z << 21);
  const bf16* Bt = Wt + ((size_t)z << 20);
  const float* bias = (z == 0) ? bq : (z == 1) ? bk : bv;
  bf16* outb = outbase + ((size_t)z << 21);

  __shared__ __align__(16) char sm[10240];
  bf16* As = (bf16*)sm;
  bf16* Bs = As + 64 * 40;
  bf16* T  = (bf16*)sm;

  const int tid = threadIdx.x, lane = tid & 63, wid = tid >> 6;
  const int q4 = lane >> 4, n16 = lane & 15;
  const int wm = wid >> 1, wn = wid & 1;
  const int m0 = blockIdx.y * 64, n0 = blockIdx.x * 64;
  const int brow = tid >> 2, bc = tid & 3;
  f32x4 acc[2][2] = {};

  uint4 aR = *(const uint4*)(A  + (size_t)(m0 + brow) * 1024 + bc * 8);
  uint4 bR = *(const uint4*)(Bt + (size_t)(n0 + brow) * 1024 + bc * 8);
  for (int kb = 0; kb < 32; ++kb) {
    __syncthreads();
    *(uint4*)(&As[brow * 40 + bc * 8]) = aR;
    *(uint4*)(&Bs[brow * 40 + bc * 8]) = bR;
    __syncthreads();
    if (kb < 31) {
      const int k1 = (kb + 1) * 32;
      aR = *(const uint4*)(A  + (size_t)(m0 + brow) * 1024 + k1 + bc * 8);
      bR = *(const uint4*)(Bt + (size_t)(n0 + brow) * 1024 + k1 + bc * 8);
    }
    bf16x8 af[2], bfv[2];
    #pragma unroll
    for (int rt = 0; rt < 2; ++rt)
      af[rt] = *(const bf16x8*)(&As[(wm * 32 + rt * 16 + n16) * 40 + q4 * 8]);
    #pragma unroll
    for (int ct = 0; ct < 2; ++ct)
      bfv[ct] = *(const bf16x8*)(&Bs[(wn * 32 + ct * 16 + n16) * 40 + q4 * 8]);
    #pragma unroll
    for (int rt = 0; rt < 2; ++rt)
      #pragma unroll
      for (int ct = 0; ct < 2; ++ct)
        acc[rt][ct] = __builtin_amdgcn_mfma_f32_16x16x32_bf16(af[rt], bfv[ct], acc[rt][ct], 0, 0, 0);
  }

  if (z < 2) {   // (B,H,S,HD)
    #pragma unroll
    for (int ct = 0; ct < 2; ++ct) {
      int col = n0 + wn * 32 + ct * 16 + n16;
      float bvl = bias[col];
      int h = col >> 6, d = col & 63;
      #pragma unroll
      for (int rt = 0; rt < 2; ++rt) {
        #pragma unroll
        for (int r = 0; r < 4; ++r) {
          int row = m0 + wm * 32 + rt * 16 + q4 * 4 + r;
          int b2 = row >> 10, s = row & 1023;
          outb[((size_t)((b2 * 16 + h) * 1024 + s) << 6) + d] =
              (bf16)(acc[rt][ct][r] + bvl);
        }
      }
    }
  } else {       // transpose -> (B,H,HD,S)
    __syncthreads();
    #pragma unroll
    for (int ct = 0; ct < 2; ++ct) {
      int cl = wn * 32 + ct * 16 + n16;
      float bvl = bias[n0 + cl];
      #pragma unroll
      for (int rt = 0; rt < 2; ++rt)
        #pragma unroll
        for (int r = 0; r < 4; ++r) {
          int rl = wm * 32 + rt * 16 + q4 * 4 + r;
          T[rl * 66 + cl] = (bf16)(acc[rt][ct][r] + bvl);
        }
    }
    __syncthreads();
    #pragma unroll
    for (int i = 0; i < 16; ++i) {
      int f = tid + i * 256;
      int nl = f >> 6, sl = f & 63;
      int col = n0 + nl, row = m0 + sl;
      int b2 = row >> 10, s = row & 1023;
      int h = col >> 6, d = col & 63;
      outb[((size_t)((b2 * 16 + h) * 64 + d) << 10) + s] = T[sl * 66 + nl];
    }
  }
}

// ---------------------------------------------------------------------------
// Output GEMM: d_out = oat(2048x1024 bf16) @ WoT + bo, f32 out. Prefetched.
// ---------------------------------------------------------------------------
__global__ __launch_bounds__(256) void out_gemm_k(
    const bf16* __restrict__ Ab, const bf16* __restrict__ Bt,
    const float* __restrict__ bias, float* __restrict__ outf)
{
  __shared__ __align__(16) char sm[10240];
  bf16* As = (bf16*)sm;
  bf16* Bs = As + 64 * 40;
  const int tid = threadIdx.x, lane = tid & 63, wid = tid >> 6;
  const int q4 = lane >> 4, n16 = lane & 15;
  const int wm = wid >> 1, wn = wid & 1;
  const int m0 = blockIdx.y * 64, n0 = blockIdx.x * 64;
  const int brow = tid >> 2, bc = tid & 3;
  f32x4 acc[2][2] = {};

  uint4 aR = *(const uint4*)(Ab + (size_t)(m0 + brow) * 1024 + bc * 8);
  uint4 bR = *(const uint4*)(Bt + (size_t)(n0 + brow) * 1024 + bc * 8);
  for (int kb = 0; kb < 32; ++kb) {
    __syncthreads();
    *(uint4*)(&As[brow * 40 + bc * 8]) = aR;
    *(uint4*)(&Bs[brow * 40 + bc * 8]) = bR;
    __syncthreads();
    if (kb < 31) {
      const int k1 = (kb + 1) * 32;
      aR = *(const uint4*)(Ab + (size_t)(m0 + brow) * 1024 + k1 + bc * 8);
      bR = *(const uint4*)(Bt + (size_t)(n0 + brow) * 1024 + k1 + bc * 8);
    }
    bf16x8 af[2], bfv[2];
    #pragma unroll
    for (int rt = 0; rt < 2; ++rt)
      af[rt] = *(const bf16x8*)(&As[(wm * 32 + rt * 16 + n16) * 40 + q4 * 8]);
    #pragma unroll
    for (int ct = 0; ct < 2; ++ct)
      bfv[ct] = *(const bf16x8*)(&Bs[(wn * 32 + ct * 16 + n16) * 40 + q4 * 8]);
    #pragma unroll
    for (int rt = 0; rt < 2; ++rt)
      #pragma unroll
      for (int ct = 0; ct < 2; ++ct)
        acc[rt][ct] = __builtin_amdgcn_mfma_f32_16x16x32_bf16(af[rt], bfv[ct], acc[rt][ct], 0, 0, 0);
  }
  #pragma unroll
  for (int ct = 0; ct < 2; ++ct) {
    int col = n0 + wn * 32 + ct * 16 + n16;
    float bvl = bias[col];
    #pragma unroll
    for (int rt = 0; rt < 2; ++rt)
      #pragma unroll
      for (int r = 0; r < 4; ++r) {
        int row = m0 + wm * 32 + rt * 16 + q4 * 4 + r;
        outf[(size_t)row * 1024 + col] = acc[rt][ct][r] + bvl;
      }
  }
}

// ---------------------------------------------------------------------------
// per-(b,h,ktile) column sums of v + suffix scan
// ---------------------------------------------------------------------------
__global__ void vtile_sum_k(const bf16* __restrict__ vT, float* __restrict__ Tsum)
{
  int kt = blockIdx.x, h = blockIdx.y, b = blockIdx.z, d = threadIdx.x;
  const bf16* p = vT + (((size_t)(b * 16 + h) * 64 + d) << 10) + kt * 64;
  float s = 0.f;
  #pragma unroll 8
  for (int i = 0; i < 64; ++i) s += (float)p[i];
  Tsum[((b * 16 + h) * 16 + kt) * 64 + d] = s;
}

__global__ void vtail_k(const float* __restrict__ Tsum, float* __restrict__ Vtail)
{
  int h = blockIdx.x, b = blockIdx.y, d = threadIdx.x;
  float c = 0.f;
  Vtail[((b * 16 + h) * 17 + 16) * 64 + d] = 0.f;
  for (int kt = 15; kt >= 0; --kt) {
    c += Tsum[((b * 16 + h) * 16 + kt) * 64 + d];
    Vtail[((b * 16 + h) * 17 + kt) * 64 + d] = c;
  }
}

// ---------------------------------------------------------------------------
// K2: logits + 3x3 conv -> P = exp(conv - tile_row_max) in bf16, plus
// (mxt, sumP) per tile row. Compact grid: x = linear active-tile index (151).
// ---------------------------------------------------------------------------
__global__ __launch_bounds__(320) void logits_conv_k(
    const bf16* __restrict__ qh, const bf16* __restrict__ kh,
    const float* __restrict__ kq_w, const float* __restrict__ kq_b,
    bf16* __restrict__ conv_out, float* __restrict__ tstats)
{
  // decode (qt, ct) from linear tile index
  const int tt = blockIdx.x;
  int qt = 0, base = 0;
  while (qt < 15 && base + qt + 2 <= tt) { base += qt + 2; ++qt; }
  const int ct = tt - base;
  const int h = blockIdx.y, b = blockIdx.z;
  const int q0 = qt * 64, c0 = ct * 64;
  __shared__ float Ls[66 * 68];   // rows q0-2..q0+63, cols c0-1..c0+64
  const int tid = threadIdx.x;
  const int lane = tid & 63, wid = tid >> 6;   // 5 waves, wave = 16-row stripe
  const int q4 = lane >> 4, n16 = lane & 15;
  const bf16* qb = qh + ((size_t)(b * 16 + h) << 16);
  const bf16* kb = kh + ((size_t)(b * 16 + h) << 16);

  const int ar = q0 - 2 + wid * 16 + n16;
  const int arc = min(max(ar, 0), 1023);
  bf16x8 a0 = *(const bf16x8*)(qb + arc * 64 + q4 * 8);
  bf16x8 a1 = *(const bf16x8*)(qb + arc * 64 + 32 + q4 * 8);
  uint4 bl[10];
  #pragma unroll
  for (int c5 = 0; c5 < 5; ++c5) {
    int brc = min(max(c0 - 1 + c5 * 16 + n16, 0), 1023);
    bl[c5 * 2]     = *(const uint4*)(kb + brc * 64 + q4 * 8);
    bl[c5 * 2 + 1] = *(const uint4*)(kb + brc * 64 + 32 + q4 * 8);
  }
  f32x4 acc[5] = {};
  #pragma unroll
  for (int c5 = 0; c5 < 5; ++c5) {
    acc[c5] = __builtin_amdgcn_mfma_f32_16x16x32_bf16(a0, *(const bf16x8*)&bl[c5 * 2],     acc[c5], 0, 0, 0);
    acc[c5] = __builtin_amdgcn_mfma_f32_16x16x32_bf16(a1, *(const bf16x8*)&bl[c5 * 2 + 1], acc[c5], 0, 0, 0);
  }
  #pragma unroll
  for (int c5 = 0; c5 < 5; ++c5) {
    #pragma unroll
    for (int r = 0; r < 4; ++r) {
      int Lrow = wid * 16 + q4 * 4 + r;
      int Lcol = c5 * 16 + n16;
      if (Lrow < 66 && Lcol < 66) {
        int rg = q0 - 2 + Lrow;
        int cg = c0 - 1 + Lcol;
        float v = (cg >= 0 && cg <= rg) ? acc[c5][r] * 0.125f : 0.f;
        Ls[Lrow * 68 + Lcol] = v;
      }
    }
  }
  __syncthreads();

  if (tid < 256) {
    float w9[9];
    #pragma unroll
    for (int i = 0; i < 9; ++i) w9[i] = kq_w[h * 9 + i];
    const float bb = kq_b[h];
    const size_t tplane = (size_t)(b * 16 + h) * 151 + base + ct;
    bf16* tb = conv_out + tplane * 4096;
    float2* st = (float2*)tstats + tplane * 64;

    const int r = tid >> 2, qr = tid & 3;   // output row, 16-col quarter
    float4 R0[5], R1[5], R2[5];
    const float* L0 = &Ls[r * 68 + qr * 16];
    #pragma unroll
    for (int i = 0; i < 5; ++i) {
      R0[i] = *(const float4*)(L0 + i * 4);
      R1[i] = *(const float4*)(L0 + 68 + i * 4);
      R2[i] = *(const float4*)(L0 + 136 + i * 4);
    }
    const float* f0 = (const float*)R0;
    const float* f1 = (const float*)R1;
    const float* f2 = (const float*)R2;
    float o[16];
    #pragma unroll
    for (int jj = 0; jj < 16; ++jj)
      o[jj] = bb + w9[0]*f0[jj] + w9[1]*f0[jj+1] + w9[2]*f0[jj+2]
                 + w9[3]*f1[jj] + w9[4]*f1[jj+1] + w9[5]*f1[jj+2]
                 + w9[6]*f2[jj] + w9[7]*f2[jj+1] + w9[8]*f2[jj+2];
    // row max across the 4 lanes sharing this row
    float mx = o[0];
    #pragma unroll
    for (int jj = 1; jj < 16; ++jj) mx = fmaxf(mx, o[jj]);
    mx = fmaxf(mx, __shfl_xor(mx, 1));
    mx = fmaxf(mx, __shfl_xor(mx, 2));
    // P = exp(o - mx), rounded to bf16; sum over rounded values
    unsigned int p[8];
    #pragma unroll
    for (int jj = 0; jj < 8; ++jj)
      p[jj] = cvt_pk_bf16(__expf(o[2*jj] - mx), __expf(o[2*jj+1] - mx));
    *(uint4*)(tb + (size_t)r * 64 + qr * 16)     = *(const uint4*)&p[0];
    *(uint4*)(tb + (size_t)r * 64 + qr * 16 + 8) = *(const uint4*)&p[4];
    float s = 0.f;
    #pragma unroll
    for (int jj = 0; jj < 8; ++jj) s += bf_lo(p[jj]) + bf_hi(p[jj]);
    s += __shfl_xor(s, 1);
    s += __shfl_xor(s, 2);
    if (qr == 0) st[r] = make_float2(mx, s);
  }
}

// ---------------------------------------------------------------------------
// K3a: combine per-tile stats -> per-row (max m, 1/l) incl. constant tail
// ---------------------------------------------------------------------------
__global__ __launch_bounds__(256) void combine_k(
    const float* __restrict__ tstats, const float* __restrict__ kq_b,
    float* __restrict__ rs)
{
  const int ridx = blockIdx.x * 256 + threadIdx.x;
  const int q = ridx & 1023, h = (ridx >> 10) & 15, plane = ridx >> 10;
  const int qt = q >> 6;
  const int nkt = min(qt + 2, 16);
  const int Tc = 1024 - (nkt << 6);
  const float2* ts = (const float2*)tstats +
      ((size_t)plane * 151 + (size_t)(qt * (qt + 3) / 2)) * 64 + (q & 63);
  const float kb = kq_b[h];
  float mx = (Tc > 0) ? kb : -3.0e38f;
  for (int kt = 0; kt < nkt; ++kt) mx = fmaxf(mx, ts[(size_t)kt * 64].x);
  float s = (float)Tc * __expf(kb - mx);
  for (int kt = 0; kt < nkt; ++kt) {
    float2 v = ts[(size_t)kt * 64];
    s += v.y * __expf(v.x - mx);
  }
  rs[(size_t)ridx * 2]     = mx;
  rs[(size_t)ridx * 2 + 1] = 1.f / s;
}

// ---------------------------------------------------------------------------
// K3b: PV from stored P tiles, software-pipelined (explicit double buffer,
// hoisted per-kt weights). A_o = sum_j (mw[o,j]*rinv_j*exp(mxt_j-m_j))*P_j
// ---------------------------------------------------------------------------
__global__ __launch_bounds__(256) void pv_k(
    const bf16* __restrict__ conv_out, const bf16* __restrict__ vT,
    const float* __restrict__ rs, const float* __restrict__ tstats,
    const float* __restrict__ Vtail,
    const float* __restrict__ mix_w, const float* __restrict__ mix_b,
    const float* __restrict__ kq_b,
    const float* __restrict__ dyt_alpha, const float* __restrict__ dyt_w,
    const float* __restrict__ dyt_b, const float* __restrict__ depth_scale,
    bf16* __restrict__ out_attn)
{
  const int qt16 = blockIdx.x, g = blockIdx.y, b = blockIdx.z;
  const int qt = qt16 >> 2;
  const int nkt = min(qt + 2, 16);
  const int Tc = 1024 - (nkt << 6);
  const int tid = threadIdx.x, lane = tid & 63, wid = tid >> 6;
  const int q4 = lane >> 4, n16 = lane & 15;
  const int oo = wid >> 1, kh = wid & 1;
  const int h0 = 2 * g, ho = h0 + oo;
  const int strow = (qt16 & 3) * 16;
  const size_t tbase = (size_t)(qt * (qt + 3) / 2);

  const int qrow = qt16 * 16 + n16;
  const float2 r0 = *(const float2*)(rs + ((((size_t)(b * 16 + h0)     << 10) + qrow) << 1));
  const float2 r1 = *(const float2*)(rs + ((((size_t)(b * 16 + h0 + 1) << 10) + qrow) << 1));
  const float m0 = r0.x, m1 = r1.x;
  const float mwa = mix_w[ho * 2 + 0], mwb = mix_w[ho * 2 + 1];
  const float wa = mwa * r0.y, wb = mwb * r1.y;   // mw * rinv

  const bf16* cb0 = conv_out +
      ((size_t)(b * 16 + h0) * 151 + tbase) * 4096 + strow * 64 + n16 * 64 + q4 * 8;
  const bf16* cb1 = cb0 + (size_t)151 * 4096;
  const float2* ts0 = (const float2*)tstats +
      ((size_t)(b * 16 + h0) * 151 + tbase) * 64 + strow + n16;
  const float2* ts1 = ts0 + (size_t)151 * 64;
  const bf16* vb  = vT + ((size_t)(b * 16 + ho) << 16);

  // #kt this wave handles: kt = kh + 2*i, i in [0, niter)
  const int niter = (nkt - kh + 1) >> 1;

  // ---- hoist all per-kt weights (16 independent loads in flight) ----
  float wk0[8], wk1[8];
  #pragma unroll
  for (int i = 0; i < 8; ++i) {
    int ktc = (i < niter) ? (kh + 2 * i) : 0;   // clamp: value unused if i>=niter
    wk0[i] = wa * __expf(ts0[(size_t)ktc * 64].x - m0);
    wk1[i] = wb * __expf(ts1[(size_t)ktc * 64].x - m1);
  }

  // ---- explicit double-buffered, fully-unrolled k-loop ----
  uint4 c0b[2][2], c1b[2][2];
  bf16x8 bvb[2][2][4];
  f32x4 acc[4] = {};

#define PV_LOAD(I, BUF) {                                                     \
    const int kt_ = kh + 2 * (I);                                             \
    c0b[BUF][0] = *(const uint4*)(cb0 + (size_t)kt_ * 4096);                  \
    c0b[BUF][1] = *(const uint4*)(cb0 + (size_t)kt_ * 4096 + 32);             \
    c1b[BUF][0] = *(const uint4*)(cb1 + (size_t)kt_ * 4096);                  \
    c1b[BUF][1] = *(const uint4*)(cb1 + (size_t)kt_ * 4096 + 32);             \
    _Pragma("unroll")                                                         \
    for (int kk = 0; kk < 2; ++kk)                                            \
      _Pragma("unroll")                                                       \
      for (int ctt = 0; ctt < 4; ++ctt)                                       \
        bvb[BUF][kk][ctt] = *(const bf16x8*)(vb +                             \
            (size_t)(ctt * 16 + n16) * 1024 + kt_ * 64 + kk * 32 + q4 * 8);   \
  }

#define PV_COMP(I, BUF) {                                                     \
    const float w0_ = wk0[I], w1_ = wk1[I];                                   \
    _Pragma("unroll")                                                         \
    for (int kk = 0; kk < 2; ++kk) {                                          \
      bf16x8 af;                                                              \
      const unsigned int* u0 = (const unsigned int*)&c0b[BUF][kk];            \
      const unsigned int* u1 = (const unsigned int*)&c1b[BUF][kk];            \
      _Pragma("unroll")                                                       \
      for (int i2 = 0; i2 < 4; ++i2) {                                        \
        float a0 = w0_ * bf_lo(u0[i2]) + w1_ * bf_lo(u1[i2]);                 \
        float a1 = w0_ * bf_hi(u0[i2]) + w1_ * bf_hi(u1[i2]);                 \
        ((unsigned int*)&af)[i2] = cvt_pk_bf16(a0, a1);                       \
      }                                                                       \
      _Pragma("unroll")                                                       \
      for (int ctt = 0; ctt < 4; ++ctt)                                       \
        acc[ctt] = __builtin_amdgcn_mfma_f32_16x16x32_bf16(af, bvb[BUF][kk][ctt], acc[ctt], 0, 0, 0); \
    }                                                                         \
  }

  PV_LOAD(0, 0);
  #pragma unroll
  for (int i = 0; i < 8; ++i) {
    if (i < niter) {
      if (i + 1 < niter) PV_LOAD(i + 1, (i + 1) & 1);
      PV_COMP(i, i & 1);
    }
  }
#undef PV_LOAD
#undef PV_COMP

  __shared__ float Pp[2][16][64];
  if (kh == 1) {
    #pragma unroll
    for (int ctt = 0; ctt < 4; ++ctt)
      #pragma unroll
      for (int r = 0; r < 4; ++r)
        Pp[oo][q4 * 4 + r][ctt * 16 + n16] = acc[ctt][r];
  }
  __syncthreads();
  if (kh == 1) return;
  #pragma unroll
  for (int ctt = 0; ctt < 4; ++ctt)
    #pragma unroll
    for (int r = 0; r < 4; ++r)
      acc[ctt][r] += Pp[oo][q4 * 4 + r][ctt * 16 + n16];

  const float kqb0 = kq_b[h0], kqb1 = kq_b[h0 + 1];
  float tw[4];
  #pragma unroll
  for (int r = 0; r < 4; ++r) {
    int qr = qt16 * 16 + q4 * 4 + r;
    float2 s0 = *(const float2*)(rs + ((((size_t)(b * 16 + h0)     << 10) + qr) << 1));
    float2 s1 = *(const float2*)(rs + ((((size_t)(b * 16 + h0 + 1) << 10) + qr) << 1));
    tw[r] = (Tc > 0) ? (mwa * s0.y * __expf(kqb0 - s0.x) +
                        mwb * s1.y * __expf(kqb1 - s1.x)) : 0.f;
  }
  const float mb = mix_b[ho];
  const float alpha = dyt_alpha[0], dsc = depth_scale[0];
  const float* vt = Vtail + (size_t)(b * 16 + ho) * 17 * 64;
  #pragma unroll
  for (int ctt = 0; ctt < 4; ++ctt) {
    int d = ctt * 16 + n16;
    float vtn = vt[(size_t)nkt * 64 + d];
    float vt0 = vt[d];
    float wgt = dyt_w[d], bds = dyt_b[d];
    #pragma unroll
    for (int r = 0; r < 4; ++r) {
      float v = acc[ctt][r] + tw[r] * vtn + mb * vt0;
      float e = __expf(2.f * alpha * v);
      float th = 1.f - 2.f / (e + 1.f);
      float y = (th * wgt + bds) * dsc;
      int qr = qt16 * 16 + q4 * 4 + r;
      out_attn[(((size_t)(b * 1024 + qr)) << 10) + ho * 64 + d] = (bf16)y;
    }
  }
}

// ---------------------------------------------------------------------------
extern "C" void kernel_launch(void* const* d_in, const int* in_sizes, int n_in,
                              void* d_out, int out_size, void* d_ws, size_t ws_size,
                              hipStream_t stream) {
  const float* Q    = (const float*)d_in[0];
  const float* Kx   = (const float*)d_in[1];
  const float* V    = (const float*)d_in[2];
  const float* Wq   = (const float*)d_in[3];
  const float* bq   = (const float*)d_in[4];
  const float* Wk   = (const float*)d_in[5];
  const float* bk   = (const float*)d_in[6];
  const float* Wv   = (const float*)d_in[7];
  const float* bv   = (const float*)d_in[8];
  const float* Wo   = (const float*)d_in[9];
  const float* bo   = (const float*)d_in[10];
  const float* kq_w = (const float*)d_in[11];
  const float* kq_b = (const float*)d_in[12];
  const float* mixw = (const float*)d_in[13];
  const float* mixb = (const float*)d_in[14];
  const float* dyta = (const float*)d_in[15];
  const float* dytw = (const float*)d_in[16];
  const float* dytb = (const float*)d_in[17];
  const float* dsc  = (const float*)d_in[18];

  char* ws = (char*)d_ws;
  bf16* qh     = (bf16*)(ws);                              // 4 MB
  bf16* kh     = (bf16*)(ws + (size_t)(4  << 20));         // 4 MB
  bf16* vT     = (bf16*)(ws + (size_t)(8  << 20));         // 4 MB
  float* tstat = (float*)(ws + (size_t)(12 << 20));        // 2.42 MB (alive thru pv)
  float* Vtail = (float*)(ws + (size_t)(16 << 20));        // 136 KB
  float* Tsum  = (float*)(ws + (size_t)(16 << 20) + (256 << 10)); // 128 KB
  float* rsbuf = (float*)(ws + (size_t)(16 << 20) + (512 << 10)); // 256 KB
  bf16* WtT    = (bf16*)(ws + (size_t)(17 << 20));         // 8 MB (4 planes x 2MB)
  bf16* oat    = (bf16*)(ws + (size_t)(17 << 20));         // 4 MB, aliases Wq/Wk planes (dead after proj)
  bf16* conv   = (bf16*)(ws + (size_t)(25 << 20));         // 39.58 MB (P tiles)
  bf16* Abf    = (bf16*)(ws + (size_t)(50 << 20));         // 12 MB, inside conv region (dead after proj)

  wtr_k<<<dim3(16, 16, 4), 256, 0, stream>>>(Wq, Wk, Wv, Wo, WtT);
  cvt_in_k<<<dim3(3072), 256, 0, stream>>>(Q, Kx, V, Abf);
  proj_gemm_k<<<dim3(16, 32, 3), 256, 0, stream>>>(Abf, WtT, bq, bk, bv, qh);
  vtile_sum_k<<<dim3(16, 16, 2), 64, 0, stream>>>(vT, Tsum);
  vtail_k<<<dim3(16, 2), 64, 0, stream>>>(Tsum, Vtail);
  logits_conv_k<<<dim3(151, 16, 2), 320, 0, stream>>>(qh, kh, kq_w, kq_b, conv, tstat);
  combine_k<<<dim3(128), 256, 0, stream>>>(tstat, kq_b, rsbuf);
  pv_k<<<dim3(64, 8, 2), 256, 0, stream>>>(conv, vT, rsbuf, tstat, Vtail, mixw, mixb, kq_b,
                                           dyta, dytw, dytb, dsc, oat);
  out_gemm_k<<<dim3(16, 32), 256, 0, stream>>>(oat, WtT + ((size_t)3 << 20), bo, (float*)d_out);
}